// Round 15
// baseline (386.838 us; speedup 1.0000x reference)
//
#include <hip/hip_runtime.h>
#include <cstdint>
#include <cstddef>

#define DIM 256
#define NH 4
#define W 8
#define EB 16
#define SCALE 0.125f

typedef __bf16 bf16x8 __attribute__((ext_vector_type(8)));
typedef float f32x4 __attribute__((ext_vector_type(4)));
typedef _Float16 h16x2 __attribute__((ext_vector_type(2)));
typedef unsigned int u32x2 __attribute__((ext_vector_type(2)));

__device__ __forceinline__ f32x4 ld4(const float* p) { return *(const f32x4*)p; }
__device__ __forceinline__ f32x4 ld4_nt(const float* p) {
  return __builtin_nontemporal_load((const f32x4*)p);
}
__device__ __forceinline__ unsigned short f2b(float f) {
  __bf16 b = (__bf16)f;
  return __builtin_bit_cast(unsigned short, b);
}
__device__ __forceinline__ unsigned short f2h(float f) {
  _Float16 h = (_Float16)f;
  return __builtin_bit_cast(unsigned short, h);
}
__device__ __forceinline__ unsigned int pk2(float a, float b) {
  return __builtin_bit_cast(unsigned int, __builtin_amdgcn_cvt_pkrtz(a, b));
}
__device__ __forceinline__ h16x2 uh(unsigned int u) {
  return __builtin_bit_cast(h16x2, u);
}

// ---------------------------------------------------------------------------
// Pack Wq (x SCALE) and Wk into MFMA-B-fragment bf16 layouts (pure permute).
// ---------------------------------------------------------------------------
__global__ void precomp_pack(const float* __restrict__ Wq, const float* __restrict__ Wk,
                             unsigned short* __restrict__ Bqsw,
                             unsigned short* __restrict__ Bksw) {
  int i = blockIdx.x * 256 + threadIdx.x;   // 0..65535
  int j = i & 7, lane = (i >> 3) & 63, nt = (i >> 9) & 15;
  int col15 = lane & 15, kg = lane >> 4;
  int kt = i >> 13;                          // 0..7
  Bqsw[i] = f2b(SCALE * Wq[(nt * 16 + col15) * 256 + kt * 32 + kg * 8 + j]);
  int kt2 = (i >> 13) & 1, n = i >> 14;
  Bksw[i] = f2b(Wk[(n * 64 + kt2 * 32 + kg * 8 + j) * 256 + nt * 16 + col15]);
}

// ---------------------------------------------------------------------------
// wvo[n][256] = Wv_n^T Wo_n (f32), consts[0] = bo + bv.Wo
// ---------------------------------------------------------------------------
__global__ void precomp_b(const float* __restrict__ Wv, const float* __restrict__ bv,
                          const float* __restrict__ Wo, const float* __restrict__ bo,
                          float* __restrict__ wvo, float* __restrict__ consts) {
  int t = threadIdx.x;
  for (int col = t; col < 1024; col += 256) {
    int n = col >> 8, b = col & 255;
    float sw = 0.f;
#pragma unroll 8
    for (int d = 0; d < 64; ++d)
      sw += Wv[(n * 64 + d) * 256 + b] * Wo[n * 64 + d];
    wvo[col] = sw;
  }
  if (t == 0) {
    float s = bo[0];
    for (int d = 0; d < 256; ++d) s += bv[d] * Wo[d];
    consts[0] = s;
  }
}

// ---------------------------------------------------------------------------
// Fused main kernel (R14 + two-edge interleaved epilogue).
//  phase 1 (rank-64): GEMM1 q = SCALE*(h@Wq^T+bq); q->q_lds (intra-wave);
//           r = q.bk -> r_lds; GEMM2 t_n = q_n@Wk_n -> t_lds (f16).
//  ONE barrier (lgkmcnt only; global loads stay in flight).
//  phase 2: edges processed in PAIRS — cvt f32->f16 packed first (frees the
//           f32 ev buffers, which are immediately reused to issue the next
//           pair's loads), then both edges' fdot2 chains + shuffle trees
//           interleaved (2x ILP on every dependent level). No-max softmax.
// ---------------------------------------------------------------------------
__global__ __launch_bounds__(256, 3) void fused_main(
    const float* __restrict__ h_i, const float* __restrict__ evol,
    const float* __restrict__ evt, const float* __restrict__ var_i,
    const float* __restrict__ var_j, const float* __restrict__ cur_t,
    const float* __restrict__ tdp, const float* __restrict__ Wu,
    const float* __restrict__ bup, const float* __restrict__ bq,
    const float* __restrict__ bk, const unsigned short* __restrict__ Bqsw,
    const unsigned short* __restrict__ Bksw, const float* __restrict__ wvo,
    const float* __restrict__ consts, float* __restrict__ out) {

  __shared__ unsigned short t_lds[EB * 1024];   // 32 KB (f16 bits, [m][n*256+d])
  __shared__ unsigned short q_lds[4 * 1152];    // 9 KB  (per-wave q bounce, bf16)
  __shared__ unsigned int wvou_lds[640];        // 2.5 KB (f16x2: wvo|Wu)
  __shared__ float r_lds[EB][NH];               // 256 B

  const int tid = threadIdx.x;
  const int wid = tid >> 6;        // wave index
  const int lane = tid & 63;
  const int e0 = blockIdx.x * EB;
  const int eb = e0 + wid * 4;     // this wave's first edge

  const int col15 = lane & 15;
  const int kg = lane >> 4;
  const int oct = lane >> 3;       // window index (phase 2)
  const int c = lane & 7;          // dim-chunk index (phase 2)

#define EV_ISSUE(EV, el) {                                                     \
    const float* _p = evol + (size_t)(eb + (el)) * 2048 + oct * 256 + c * 4;   \
    _Pragma("unroll") for (int k = 0; k < 8; ++k) EV[k] = ld4_nt(_p + k * 32); }

  // ---- edge 0 ev issued NOW: latency hides under all of phase 1 ----
  f32x4 evA[8], evB[8];
  EV_ISSUE(evA, 0)

  // wvo/Wu -> LDS as packed f16 pairs (block-wide; visible after barrier)
  for (int i = tid; i < 640; i += 256) {
    float a = (i < 512) ? wvo[2 * i] : Wu[2 * i - 1024];
    float b = (i < 512) ? wvo[2 * i + 1] : Wu[2 * i + 1 - 1024];
    wvou_lds[i] = pk2(a, b);
  }

  // ---------------- phase 1a: GEMM1 q = SCALE*(h @ Wq^T + bq) ----------------
  f32x4 zero4 = {0.f, 0.f, 0.f, 0.f};
  f32x4 qacc[4];
#pragma unroll
  for (int i = 0; i < 4; ++i) qacc[i] = zero4;

  const float* hrow = h_i + (size_t)(e0 + col15) * DIM + kg * 8;
  const bf16x8* bq_b = (const bf16x8*)Bqsw;

#pragma unroll
  for (int ks = 0; ks < 8; ++ks) {
    f32x4 a0 = ld4(hrow + ks * 32);
    f32x4 a1 = ld4(hrow + ks * 32 + 4);
    bf16x8 af;
#pragma unroll
    for (int j = 0; j < 4; ++j) { af[j] = (__bf16)a0[j]; af[j + 4] = (__bf16)a1[j]; }
    const bf16x8* bb = bq_b + (size_t)(ks * 16 + wid * 4) * 64 + lane;
#pragma unroll
    for (int ntl = 0; ntl < 4; ++ntl)
      qacc[ntl] = __builtin_amdgcn_mfma_f32_16x16x32_bf16(af, bb[(size_t)ntl * 64], qacc[ntl], 0, 0, 0);
  }

  // q -> LDS bounce (row stride 144 B), + SCALE*bq   [intra-wave only]
  char* qregion = (char*)q_lds + wid * 2304;
#pragma unroll
  for (int ntl = 0; ntl < 4; ++ntl) {
    float bqv = SCALE * bq[wid * 64 + ntl * 16 + col15];
#pragma unroll
    for (int r = 0; r < 4; ++r)
      *(unsigned short*)(qregion + (kg * 4 + r) * 144 + (ntl * 16 + col15) * 2) =
          f2b(qacc[ntl][r] + bqv);
  }
  asm volatile("s_waitcnt lgkmcnt(0)" ::: "memory");

  bf16x8 qa[2];
  qa[0] = *(const bf16x8*)(qregion + col15 * 144 + kg * 16);
  qa[1] = *(const bf16x8*)(qregion + col15 * 144 + 64 + kg * 16);

  // r[edge][n] = q_n . bk_n   (zero-valued here; handled generally)
  {
    float rp = 0.f;
#pragma unroll
    for (int kt = 0; kt < 2; ++kt) {
      f32x4 b0 = ld4(bk + wid * 64 + kt * 32 + kg * 8);
      f32x4 b1 = ld4(bk + wid * 64 + kt * 32 + kg * 8 + 4);
#pragma unroll
      for (int j = 0; j < 4; ++j)
        rp += (float)qa[kt][j] * b0[j] + (float)qa[kt][j + 4] * b1[j];
    }
    rp += __shfl_xor(rp, 16);
    rp += __shfl_xor(rp, 32);
    if (lane < 16) r_lds[lane][wid] = rp;
  }

  // ---------------- phase 1b: GEMM2 t_n = q_n @ Wk_n ----------------
  f32x4 tacc[16];
#pragma unroll
  for (int i = 0; i < 16; ++i) tacc[i] = zero4;
  const bf16x8* bk_b = (const bf16x8*)Bksw;
#pragma unroll
  for (int kt = 0; kt < 2; ++kt) {
    const bf16x8* bb = bk_b + (size_t)((wid * 2 + kt) * 16) * 64 + lane;
#pragma unroll
    for (int nt = 0; nt < 16; ++nt)
      tacc[nt] = __builtin_amdgcn_mfma_f32_16x16x32_bf16(qa[kt], bb[(size_t)nt * 64], tacc[nt], 0, 0, 0);
  }
  // D: edge = kg*4 + r, dim = wid*256 + nt*16 + col15  -> store as f16
#pragma unroll
  for (int nt = 0; nt < 16; ++nt) {
    int dim = wid * 256 + nt * 16 + col15;
#pragma unroll
    for (int r = 0; r < 4; ++r)
      t_lds[(kg * 4 + r) * 1024 + dim] = f2h(tacc[nt][r]);
  }

  // ---- edge 1 ev issued before the barrier (stays in flight across it) ----
  EV_ISSUE(evB, 1)

  // ---------------- the ONE barrier (t_lds/r_lds/wvou cross-wave) -----------
  asm volatile("s_waitcnt lgkmcnt(0)" ::: "memory");
  __builtin_amdgcn_s_barrier();
  __builtin_amdgcn_sched_barrier(0);

  // ---------------- phase 2: pairs of edges, chains interleaved -------------
  const float tdec = fabsf(tdp[0]);
  const float buv = bup[0];
  const float c0 = consts[0];

#define CVT16(EVH, EV)                                                         \
  _Pragma("unroll") for (int k = 0; k < 8; ++k) {                              \
    EVH[2 * k] = pk2(EV[k][0], EV[k][1]);                                      \
    EVH[2 * k + 1] = pk2(EV[k][2], EV[k][3]);                                  \
  }

#define DOTS(DT, DG, DU, EVH, em)                                              \
  _Pragma("unroll") for (int n = 0; n < 4; ++n) {                              \
    const u32x2* tb2 = (const u32x2*)&t_lds[(em) * 1024 + n * 256 + c * 4];    \
    const u32x2* wb2 = (const u32x2*)&wvou_lds[n * 128 + c * 2];               \
    _Pragma("unroll") for (int k = 0; k < 8; ++k) {                            \
      u32x2 tw = tb2[k * 8];                                                   \
      u32x2 ww = wb2[k * 8];                                                   \
      DT[n] = __builtin_amdgcn_fdot2(uh(EVH[2 * k]), uh(tw[0]), DT[n], false); \
      DT[n] = __builtin_amdgcn_fdot2(uh(EVH[2 * k + 1]), uh(tw[1]), DT[n], false); \
      DG[n] = __builtin_amdgcn_fdot2(uh(EVH[2 * k]), uh(ww[0]), DG[n], false); \
      DG[n] = __builtin_amdgcn_fdot2(uh(EVH[2 * k + 1]), uh(ww[1]), DG[n], false); \
    }                                                                          \
  }                                                                            \
  {                                                                            \
    const u32x2* ub2 = (const u32x2*)&wvou_lds[512 + c * 2];                   \
    _Pragma("unroll") for (int k = 0; k < 8; ++k) {                            \
      u32x2 uw = ub2[k * 8];                                                   \
      DU = __builtin_amdgcn_fdot2(uh(EVH[2 * k]), uh(uw[0]), DU, false);       \
      DU = __builtin_amdgcn_fdot2(uh(EVH[2 * k + 1]), uh(uw[1]), DU, false);   \
    }                                                                          \
  }

  // PAIR processes two edges (elX, elY) with interleaved chains.
#define PAIR(EVHX, EVHY, elX, elY)                                             \
  {                                                                            \
    const int emX = wid * 4 + (elX), emY = wid * 4 + (elY);                    \
    const int eX = e0 + emX, eY = e0 + emY;                                    \
    f32x4 viX = ld4_nt(var_i + (size_t)eX * DIM + lane * 4);                   \
    f32x4 vjX = ld4_nt(var_j + (size_t)eX * DIM + lane * 4);                   \
    f32x4 viY = ld4_nt(var_i + (size_t)eY * DIM + lane * 4);                   \
    f32x4 vjY = ld4_nt(var_j + (size_t)eY * DIM + lane * 4);                   \
    float tevX = evt[(size_t)eX * W + oct], ctvX = cur_t[eX];                  \
    float tevY = evt[(size_t)eY * W + oct], ctvY = cur_t[eY];                  \
    float dtX[4] = {0.f, 0.f, 0.f, 0.f}, dgX[4] = {0.f, 0.f, 0.f, 0.f};        \
    float dtY[4] = {0.f, 0.f, 0.f, 0.f}, dgY[4] = {0.f, 0.f, 0.f, 0.f};        \
    float duX = 0.f, duY = 0.f;                                                \
    DOTS(dtX, dgX, duX, EVHX, emX)                                             \
    DOTS(dtY, dgY, duY, EVHY, emY)                                             \
    _Pragma("unroll") for (int s = 1; s < 8; s <<= 1) {                        \
      _Pragma("unroll") for (int n = 0; n < 4; ++n) {                          \
        dtX[n] += __shfl_xor(dtX[n], s);                                       \
        dgX[n] += __shfl_xor(dgX[n], s);                                       \
        dtY[n] += __shfl_xor(dtY[n], s);                                       \
        dgY[n] += __shfl_xor(dgY[n], s);                                       \
      }                                                                        \
      duX += __shfl_xor(duX, s);                                               \
      duY += __shfl_xor(duY, s);                                               \
    }                                                                          \
    float tbX = -tdec * fmaxf(ctvX - tevX, 0.f);                               \
    float tbY = -tdec * fmaxf(ctvY - tevY, 0.f);                               \
    float unX = 1.f / (1.f + __expf(-(duX + buv)));                            \
    float unY = 1.f / (1.f + __expf(-(duY + buv)));                            \
    float psX[4], pgX[4], psY[4], pgY[4];                                      \
    _Pragma("unroll") for (int n = 0; n < 4; ++n) {                            \
      float pX = __expf((dtX[n] + r_lds[emX][n] + tbX) * unX);                 \
      float pY = __expf((dtY[n] + r_lds[emY][n] + tbY) * unY);                 \
      psX[n] = pX; pgX[n] = pX * dgX[n];                                       \
      psY[n] = pY; pgY[n] = pY * dgY[n];                                       \
    }                                                                          \
    _Pragma("unroll") for (int s = 8; s < 64; s <<= 1)                         \
      _Pragma("unroll") for (int n = 0; n < 4; ++n) {                          \
        psX[n] += __shfl_xor(psX[n], s);                                       \
        pgX[n] += __shfl_xor(pgX[n], s);                                       \
        psY[n] += __shfl_xor(psY[n], s);                                       \
        pgY[n] += __shfl_xor(pgY[n], s);                                       \
      }                                                                        \
    float lgX = pgX[0] / psX[0] + pgX[1] / psX[1] + pgX[2] / psX[2] + pgX[3] / psX[3] + c0; \
    float lgY = pgY[0] / psY[0] + pgY[1] / psY[1] + pgY[2] / psY[2] + pgY[3] / psY[3] + c0; \
    float siX = viX[0] + viX[1] + viX[2] + viX[3];                             \
    float sjX = vjX[0] + vjX[1] + vjX[2] + vjX[3];                             \
    float siY = viY[0] + viY[1] + viY[2] + viY[3];                             \
    float sjY = vjY[0] + vjY[1] + vjY[2] + vjY[3];                             \
    _Pragma("unroll") for (int s = 1; s < 64; s <<= 1) {                       \
      siX += __shfl_xor(siX, s); sjX += __shfl_xor(sjX, s);                    \
      siY += __shfl_xor(siY, s); sjY += __shfl_xor(sjY, s);                    \
    }                                                                          \
    if (lane == 0) {                                                           \
      float ciX = 1.f / (1.f + fmaxf(sqrtf(siX * (1.f / 256.f)), 1e-6f));      \
      float cjX = 1.f / (1.f + fmaxf(sqrtf(sjX * (1.f / 256.f)), 1e-6f));      \
      out[eX] = 1.f / (1.f + __expf(-lgX * ciX * cjX));                        \
      float ciY = 1.f / (1.f + fmaxf(sqrtf(siY * (1.f / 256.f)), 1e-6f));      \
      float cjY = 1.f / (1.f + fmaxf(sqrtf(sjY * (1.f / 256.f)), 1e-6f));      \
      out[eY] = 1.f / (1.f + __expf(-lgY * ciY * cjY));                        \
    }                                                                          \
  }

  unsigned int evhA[16], evhB[16];

  // pair (0,1): convert first (frees evA/evB), then issue edges 2,3 into them
  CVT16(evhA, evA)
  CVT16(evhB, evB)
  EV_ISSUE(evA, 2)
  EV_ISSUE(evB, 3)
  __builtin_amdgcn_sched_barrier(0);
  PAIR(evhA, evhB, 0, 1)

  // pair (2,3)
  CVT16(evhA, evA)
  CVT16(evhB, evB)
  PAIR(evhA, evhB, 2, 3)

#undef EV_ISSUE
#undef CVT16
#undef DOTS
#undef PAIR
}

extern "C" void kernel_launch(void* const* d_in, const int* in_sizes, int n_in,
                              void* d_out, int out_size, void* d_ws, size_t ws_size,
                              hipStream_t stream) {
  const float* h_i = (const float*)d_in[0];
  // d_in[1] (h_j) is unused by the reference
  const float* evol = (const float*)d_in[2];
  const float* evt = (const float*)d_in[3];
  const float* var_i = (const float*)d_in[4];
  const float* var_j = (const float*)d_in[5];
  const float* ct = (const float*)d_in[6];
  const float* Wq = (const float*)d_in[7];
  const float* bq = (const float*)d_in[8];
  const float* Wk = (const float*)d_in[9];
  const float* bk = (const float*)d_in[10];
  const float* Wv = (const float*)d_in[11];
  const float* bv = (const float*)d_in[12];
  const float* td = (const float*)d_in[13];
  const float* Wu = (const float*)d_in[14];
  const float* bu = (const float*)d_in[15];
  const float* Wo = (const float*)d_in[16];
  const float* bo = (const float*)d_in[17];
  float* out = (float*)d_out;

  char* ws = (char*)d_ws;
  unsigned short* Bqsw = (unsigned short*)ws;               // 128 KB
  unsigned short* Bksw = (unsigned short*)(ws + 131072);    // 128 KB
  float* wvo = (float*)(ws + 262144);                       // 4 KB
  float* consts = (float*)(ws + 266240);                    // 32 B

  const int E = in_sizes[6];  // 100000; EB=16 divides exactly (6250 blocks)

  precomp_pack<<<256, 256, 0, stream>>>(Wq, Wk, Bqsw, Bksw);
  precomp_b<<<1, 256, 0, stream>>>(Wv, bv, Wo, bo, wvo, consts);
  fused_main<<<E / EB, 256, 0, stream>>>(h_i, evol, evt, var_i, var_j, ct, td, Wu, bu,
                                         bq, bk, Bqsw, Bksw, wvo, consts, out);
}

// Round 16
// 249.929 us; speedup vs baseline: 1.5478x; 1.5478x over previous
//
#include <hip/hip_runtime.h>
#include <cstdint>
#include <cstddef>

#define DIM 256
#define NH 4
#define W 8
#define EB 16
#define SCALE 0.125f

typedef __bf16 bf16x8 __attribute__((ext_vector_type(8)));
typedef float f32x4 __attribute__((ext_vector_type(4)));
typedef _Float16 h16x2 __attribute__((ext_vector_type(2)));
typedef unsigned int u32x2 __attribute__((ext_vector_type(2)));

__device__ __forceinline__ f32x4 ld4(const float* p) { return *(const f32x4*)p; }
__device__ __forceinline__ f32x4 ld4_nt(const float* p) {
  return __builtin_nontemporal_load((const f32x4*)p);
}
__device__ __forceinline__ unsigned short f2b(float f) {
  __bf16 b = (__bf16)f;
  return __builtin_bit_cast(unsigned short, b);
}
__device__ __forceinline__ unsigned short f2h(float f) {
  _Float16 h = (_Float16)f;
  return __builtin_bit_cast(unsigned short, h);
}
__device__ __forceinline__ unsigned int pk2(float a, float b) {
  return __builtin_bit_cast(unsigned int, __builtin_amdgcn_cvt_pkrtz(a, b));
}
__device__ __forceinline__ h16x2 uh(unsigned int u) {
  return __builtin_bit_cast(h16x2, u);
}

// ---------------------------------------------------------------------------
// Pack Wq (x SCALE) and Wk into MFMA-B-fragment bf16 layouts (pure permute):
//  Bqsw [kt 8][nt 16][lane 64][j 8]: B[k][qcol], k=kt*32+(lane>>4)*8+j,
//       qcol=nt*16+(lane&15), val=SCALE*Wq[qcol][k]
//  Bksw [n 4][kt 2][nt 16][lane 64][j 8]: per-head B2[kk][b], kk=kt*32+...,
//       b=nt*16+(lane&15), val=Wk[n*64+kk][b]
// ---------------------------------------------------------------------------
__global__ void precomp_pack(const float* __restrict__ Wq, const float* __restrict__ Wk,
                             unsigned short* __restrict__ Bqsw,
                             unsigned short* __restrict__ Bksw) {
  int i = blockIdx.x * 256 + threadIdx.x;   // 0..65535
  int j = i & 7, lane = (i >> 3) & 63, nt = (i >> 9) & 15;
  int col15 = lane & 15, kg = lane >> 4;
  int kt = i >> 13;                          // 0..7
  Bqsw[i] = f2b(SCALE * Wq[(nt * 16 + col15) * 256 + kt * 32 + kg * 8 + j]);
  int kt2 = (i >> 13) & 1, n = i >> 14;
  Bksw[i] = f2b(Wk[(n * 64 + kt2 * 32 + kg * 8 + j) * 256 + nt * 16 + col15]);
}

// ---------------------------------------------------------------------------
// wvo[n][256] = Wv_n^T Wo_n (f32), consts[0] = bo + bv.Wo
// ---------------------------------------------------------------------------
__global__ void precomp_b(const float* __restrict__ Wv, const float* __restrict__ bv,
                          const float* __restrict__ Wo, const float* __restrict__ bo,
                          float* __restrict__ wvo, float* __restrict__ consts) {
  int t = threadIdx.x;
  for (int col = t; col < 1024; col += 256) {
    int n = col >> 8, b = col & 255;
    float sw = 0.f;
#pragma unroll 8
    for (int d = 0; d < 64; ++d)
      sw += Wv[(n * 64 + d) * 256 + b] * Wo[n * 64 + d];
    wvo[col] = sw;
  }
  if (t == 0) {
    float s = bo[0];
    for (int d = 0; d < 256; ++d) s += bv[d] * Wo[d];
    consts[0] = s;
  }
}

// ---------------------------------------------------------------------------
// Fused main kernel (R14: R13 structure; phase-2 dot engine = packed f16 fdot2).
//  phase 1 (rank-64): GEMM1 q = SCALE*(h@Wq^T+bq); q->q_lds (intra-wave);
//           r = q.bk -> r_lds; GEMM2 t_n = q_n@Wk_n -> t_lds (f16).
//  ONE barrier (lgkmcnt only; global loads stay in flight).
//  phase 2: wave owns 4 edges, all heads in-lane; ev direct from global
//           (depth-2), converted once to packed f16; dt/dg/du via
//           v_dot2_f32_f16 (2 MAC/instr, no per-element converts);
//           t/wvou from LDS (broadcast, conflict-free); no-max softmax.
// ---------------------------------------------------------------------------
__global__ __launch_bounds__(256, 3) void fused_main(
    const float* __restrict__ h_i, const float* __restrict__ evol,
    const float* __restrict__ evt, const float* __restrict__ var_i,
    const float* __restrict__ var_j, const float* __restrict__ cur_t,
    const float* __restrict__ tdp, const float* __restrict__ Wu,
    const float* __restrict__ bup, const float* __restrict__ bq,
    const float* __restrict__ bk, const unsigned short* __restrict__ Bqsw,
    const unsigned short* __restrict__ Bksw, const float* __restrict__ wvo,
    const float* __restrict__ consts, float* __restrict__ out) {

  __shared__ unsigned short t_lds[EB * 1024];   // 32 KB (f16 bits, [m][n*256+d])
  __shared__ unsigned short q_lds[4 * 1152];    // 9 KB  (per-wave q bounce, bf16)
  __shared__ unsigned int wvou_lds[640];        // 2.5 KB (f16x2: wvo|Wu)
  __shared__ float r_lds[EB][NH];               // 256 B

  const int tid = threadIdx.x;
  const int wid = tid >> 6;        // wave index
  const int lane = tid & 63;
  const int e0 = blockIdx.x * EB;
  const int eb = e0 + wid * 4;     // this wave's first edge

  const int col15 = lane & 15;
  const int kg = lane >> 4;
  const int oct = lane >> 3;       // window index (phase 2)
  const int c = lane & 7;          // dim-chunk index (phase 2)

#define EV_ISSUE(EV, el) {                                                     \
    const float* _p = evol + (size_t)(eb + (el)) * 2048 + oct * 256 + c * 4;   \
    _Pragma("unroll") for (int k = 0; k < 8; ++k) EV[k] = ld4_nt(_p + k * 32); }

  // ---- edge 0 ev issued NOW: latency hides under all of phase 1 ----
  f32x4 evA[8], evB[8];
  EV_ISSUE(evA, 0)

  // wvo/Wu -> LDS as packed f16 pairs (block-wide; visible after barrier)
  for (int i = tid; i < 640; i += 256) {
    float a = (i < 512) ? wvo[2 * i] : Wu[2 * i - 1024];
    float b = (i < 512) ? wvo[2 * i + 1] : Wu[2 * i + 1 - 1024];
    wvou_lds[i] = pk2(a, b);
  }

  // ---------------- phase 1a: GEMM1 q = SCALE*(h @ Wq^T + bq) ----------------
  f32x4 zero4 = {0.f, 0.f, 0.f, 0.f};
  f32x4 qacc[4];
#pragma unroll
  for (int i = 0; i < 4; ++i) qacc[i] = zero4;

  const float* hrow = h_i + (size_t)(e0 + col15) * DIM + kg * 8;
  const bf16x8* bq_b = (const bf16x8*)Bqsw;

#pragma unroll
  for (int ks = 0; ks < 8; ++ks) {
    f32x4 a0 = ld4(hrow + ks * 32);
    f32x4 a1 = ld4(hrow + ks * 32 + 4);
    bf16x8 af;
#pragma unroll
    for (int j = 0; j < 4; ++j) { af[j] = (__bf16)a0[j]; af[j + 4] = (__bf16)a1[j]; }
    const bf16x8* bb = bq_b + (size_t)(ks * 16 + wid * 4) * 64 + lane;
#pragma unroll
    for (int ntl = 0; ntl < 4; ++ntl)
      qacc[ntl] = __builtin_amdgcn_mfma_f32_16x16x32_bf16(af, bb[(size_t)ntl * 64], qacc[ntl], 0, 0, 0);
  }

  // q -> LDS bounce (row stride 144 B), + SCALE*bq   [intra-wave only]
  char* qregion = (char*)q_lds + wid * 2304;
#pragma unroll
  for (int ntl = 0; ntl < 4; ++ntl) {
    float bqv = SCALE * bq[wid * 64 + ntl * 16 + col15];
#pragma unroll
    for (int r = 0; r < 4; ++r)
      *(unsigned short*)(qregion + (kg * 4 + r) * 144 + (ntl * 16 + col15) * 2) =
          f2b(qacc[ntl][r] + bqv);
  }
  asm volatile("s_waitcnt lgkmcnt(0)" ::: "memory");

  bf16x8 qa[2];
  qa[0] = *(const bf16x8*)(qregion + col15 * 144 + kg * 16);
  qa[1] = *(const bf16x8*)(qregion + col15 * 144 + 64 + kg * 16);

  // r[edge][n] = q_n . bk_n   (zero-valued here; handled generally)
  {
    float rp = 0.f;
#pragma unroll
    for (int kt = 0; kt < 2; ++kt) {
      f32x4 b0 = ld4(bk + wid * 64 + kt * 32 + kg * 8);
      f32x4 b1 = ld4(bk + wid * 64 + kt * 32 + kg * 8 + 4);
#pragma unroll
      for (int j = 0; j < 4; ++j)
        rp += (float)qa[kt][j] * b0[j] + (float)qa[kt][j + 4] * b1[j];
    }
    rp += __shfl_xor(rp, 16);
    rp += __shfl_xor(rp, 32);
    if (lane < 16) r_lds[lane][wid] = rp;
  }

  // ---------------- phase 1b: GEMM2 t_n = q_n @ Wk_n ----------------
  f32x4 tacc[16];
#pragma unroll
  for (int i = 0; i < 16; ++i) tacc[i] = zero4;
  const bf16x8* bk_b = (const bf16x8*)Bksw;
#pragma unroll
  for (int kt = 0; kt < 2; ++kt) {
    const bf16x8* bb = bk_b + (size_t)((wid * 2 + kt) * 16) * 64 + lane;
#pragma unroll
    for (int nt = 0; nt < 16; ++nt)
      tacc[nt] = __builtin_amdgcn_mfma_f32_16x16x32_bf16(qa[kt], bb[(size_t)nt * 64], tacc[nt], 0, 0, 0);
  }
  // D: edge = kg*4 + r, dim = wid*256 + nt*16 + col15  -> store as f16
#pragma unroll
  for (int nt = 0; nt < 16; ++nt) {
    int dim = wid * 256 + nt * 16 + col15;
#pragma unroll
    for (int r = 0; r < 4; ++r)
      t_lds[(kg * 4 + r) * 1024 + dim] = f2h(tacc[nt][r]);
  }

  // ---- edge 1 ev issued before the barrier (stays in flight across it) ----
  EV_ISSUE(evB, 1)

  // ---------------- the ONE barrier (t_lds/r_lds/wvou cross-wave) -----------
  asm volatile("s_waitcnt lgkmcnt(0)" ::: "memory");
  __builtin_amdgcn_s_barrier();
  __builtin_amdgcn_sched_barrier(0);

  // ---------------- phase 2: per-wave 4 edges, all heads in-lane ------------
  const float tdec = fabsf(tdp[0]);
  const float buv = bup[0];
  const float c0 = consts[0];

#define EV_COMPUTE(EV, el) {                                                   \
    const int em = wid * 4 + (el);                                             \
    const int e = e0 + em;                                                     \
    f32x4 vi = ld4_nt(var_i + (size_t)e * DIM + lane * 4);                     \
    f32x4 vj = ld4_nt(var_j + (size_t)e * DIM + lane * 4);                     \
    float tev = evt[(size_t)e * W + oct];                                      \
    float ctv = cur_t[e];                                                      \
    unsigned int evh[16];                                                      \
    _Pragma("unroll") for (int k = 0; k < 8; ++k) {                            \
      evh[2 * k] = pk2(EV[k][0], EV[k][1]);                                    \
      evh[2 * k + 1] = pk2(EV[k][2], EV[k][3]);                                \
    }                                                                          \
    float dt[4] = {0.f, 0.f, 0.f, 0.f}, dg[4] = {0.f, 0.f, 0.f, 0.f};          \
    float du = 0.f;                                                            \
    _Pragma("unroll") for (int n = 0; n < 4; ++n) {                            \
      const u32x2* tb2 = (const u32x2*)&t_lds[em * 1024 + n * 256 + c * 4];    \
      const u32x2* wb2 = (const u32x2*)&wvou_lds[n * 128 + c * 2];             \
      _Pragma("unroll") for (int k = 0; k < 8; ++k) {                          \
        u32x2 tw = tb2[k * 8];                                                 \
        u32x2 ww = wb2[k * 8];                                                 \
        dt[n] = __builtin_amdgcn_fdot2(uh(evh[2 * k]), uh(tw[0]), dt[n], false); \
        dt[n] = __builtin_amdgcn_fdot2(uh(evh[2 * k + 1]), uh(tw[1]), dt[n], false); \
        dg[n] = __builtin_amdgcn_fdot2(uh(evh[2 * k]), uh(ww[0]), dg[n], false); \
        dg[n] = __builtin_amdgcn_fdot2(uh(evh[2 * k + 1]), uh(ww[1]), dg[n], false); \
      } }                                                                      \
    {                                                                          \
      const u32x2* ub2 = (const u32x2*)&wvou_lds[512 + c * 2];                 \
      _Pragma("unroll") for (int k = 0; k < 8; ++k) {                          \
        u32x2 uw = ub2[k * 8];                                                 \
        du = __builtin_amdgcn_fdot2(uh(evh[2 * k]), uh(uw[0]), du, false);     \
        du = __builtin_amdgcn_fdot2(uh(evh[2 * k + 1]), uh(uw[1]), du, false); \
      } }                                                                      \
    _Pragma("unroll") for (int s = 1; s < 8; s <<= 1) {                        \
      _Pragma("unroll") for (int n = 0; n < 4; ++n) {                          \
        dt[n] += __shfl_xor(dt[n], s);                                         \
        dg[n] += __shfl_xor(dg[n], s);                                         \
      }                                                                        \
      du += __shfl_xor(du, s);                                                 \
    }                                                                          \
    float tbias = -tdec * fmaxf(ctv - tev, 0.f);                               \
    float unc = 1.f / (1.f + __expf(-(du + buv)));                             \
    float ps[4], pg[4];                                                        \
    _Pragma("unroll") for (int n = 0; n < 4; ++n) {                            \
      float p = __expf((dt[n] + r_lds[em][n] + tbias) * unc);                  \
      ps[n] = p;                                                               \
      pg[n] = p * dg[n];                                                       \
    }                                                                          \
    _Pragma("unroll") for (int s = 8; s < 64; s <<= 1)                         \
      _Pragma("unroll") for (int n = 0; n < 4; ++n) {                          \
        ps[n] += __shfl_xor(ps[n], s);                                         \
        pg[n] += __shfl_xor(pg[n], s);                                         \
      }                                                                        \
    float logit = pg[0] / ps[0] + pg[1] / ps[1] + pg[2] / ps[2] + pg[3] / ps[3] + c0; \
    float si = vi[0] + vi[1] + vi[2] + vi[3];                                  \
    float sj = vj[0] + vj[1] + vj[2] + vj[3];                                  \
    _Pragma("unroll") for (int s = 1; s < 64; s <<= 1) {                       \
      si += __shfl_xor(si, s);                                                 \
      sj += __shfl_xor(sj, s);                                                 \
    }                                                                          \
    if (lane == 0) {                                                           \
      float ci = 1.f / (1.f + fmaxf(sqrtf(si * (1.f / 256.f)), 1e-6f));        \
      float cj = 1.f / (1.f + fmaxf(sqrtf(sj * (1.f / 256.f)), 1e-6f));        \
      out[e] = 1.f / (1.f + __expf(-logit * ci * cj));                         \
    } }

  EV_COMPUTE(evA, 0)
  EV_ISSUE(evA, 2)
  EV_COMPUTE(evB, 1)
  EV_ISSUE(evB, 3)
  EV_COMPUTE(evA, 2)
  EV_COMPUTE(evB, 3)

#undef EV_ISSUE
#undef EV_COMPUTE
}

extern "C" void kernel_launch(void* const* d_in, const int* in_sizes, int n_in,
                              void* d_out, int out_size, void* d_ws, size_t ws_size,
                              hipStream_t stream) {
  const float* h_i = (const float*)d_in[0];
  // d_in[1] (h_j) is unused by the reference
  const float* evol = (const float*)d_in[2];
  const float* evt = (const float*)d_in[3];
  const float* var_i = (const float*)d_in[4];
  const float* var_j = (const float*)d_in[5];
  const float* ct = (const float*)d_in[6];
  const float* Wq = (const float*)d_in[7];
  const float* bq = (const float*)d_in[8];
  const float* Wk = (const float*)d_in[9];
  const float* bk = (const float*)d_in[10];
  const float* Wv = (const float*)d_in[11];
  const float* bv = (const float*)d_in[12];
  const float* td = (const float*)d_in[13];
  const float* Wu = (const float*)d_in[14];
  const float* bu = (const float*)d_in[15];
  const float* Wo = (const float*)d_in[16];
  const float* bo = (const float*)d_in[17];
  float* out = (float*)d_out;

  char* ws = (char*)d_ws;
  unsigned short* Bqsw = (unsigned short*)ws;               // 128 KB
  unsigned short* Bksw = (unsigned short*)(ws + 131072);    // 128 KB
  float* wvo = (float*)(ws + 262144);                       // 4 KB
  float* consts = (float*)(ws + 266240);                    // 32 B

  const int E = in_sizes[6];  // 100000; EB=16 divides exactly (6250 blocks)

  precomp_pack<<<256, 256, 0, stream>>>(Wq, Wk, Bqsw, Bksw);
  precomp_b<<<1, 256, 0, stream>>>(Wv, bv, Wo, bo, wvo, consts);
  fused_main<<<E / EB, 256, 0, stream>>>(h_i, evol, evt, var_i, var_j, ct, td, Wu, bu,
                                         bq, bk, Bqsw, Bksw, wvo, consts, out);
}